// Round 1
// baseline (653.476 us; speedup 1.0000x reference)
//
#include <hip/hip_runtime.h>
#include <hip/hip_fp16.h>
#include <stdint.h>

typedef _Float16 f16;
typedef __attribute__((ext_vector_type(8))) _Float16 f16x8;
typedef __attribute__((ext_vector_type(4))) float f32x4;

#define D_DIM 4096
#define S_DIM 2048
#define M_DIM 8192   // B*S
#define R_DIM 16
#define KR 128       // K_experts * R
#define KTOT 4224    // D + KR
#define SCALING 2.0f

// ---- ws layout (bytes) ----
#define WS_AP    0                  // A' fp16 [8192][4224]  = 69,206,016
#define WS_WP    69206016           // W' fp16 [4096][4224]  = 34,603,008
#define WS_AH    103809024          // Ah fp16 [128][4096]   =  1,048,576
#define WS_HP    104857600          // h partials fp32 [4][8192][128] = 16,777,216
#define WS_CS    121634816          // colsum fp32 [4][4096] = 65,536
#define WS_LG    121700352          // logits fp32 [32]
#define WS_WS    121700480          // weights*2.0 fp32 [32]

__device__ __forceinline__ void load_lds16(const void* g, void* l) {
  __builtin_amdgcn_global_load_lds(
      (const __attribute__((address_space(1))) void*)g,
      (__attribute__((address_space(3))) void*)l, 16, 0, 0);
}

union H4 { f16 h[4]; ushort4 u; };

// x [8192][4096] fp32 -> A' cols 0..4095 fp16 ; accumulate per-batch column sums
__global__ void conv_x(const float* __restrict__ x, f16* __restrict__ Ap,
                       float* __restrict__ colsum) {
  int rc = blockIdx.x;              // 64-row chunk (128 chunks)
  int cc = blockIdx.y;              // 1024-col chunk (4)
  int col = cc * 1024 + threadIdx.x * 4;
  long base = (long)rc * 64 * D_DIM + col;
  float s0 = 0, s1 = 0, s2 = 0, s3 = 0;
  for (int r = 0; r < 64; ++r) {
    float4 v = *(const float4*)(x + base + (long)r * D_DIM);
    H4 t; t.h[0] = (f16)v.x; t.h[1] = (f16)v.y; t.h[2] = (f16)v.z; t.h[3] = (f16)v.w;
    *(ushort4*)((char*)Ap + ((long)(rc * 64 + r) * KTOT + col) * 2) = t.u;
    s0 += v.x; s1 += v.y; s2 += v.z; s3 += v.w;
  }
  int b = rc >> 5;                  // 2048 rows per batch
  float* cs = colsum + b * D_DIM + col;
  atomicAdd(cs + 0, s0); atomicAdd(cs + 1, s1);
  atomicAdd(cs + 2, s2); atomicAdd(cs + 3, s3);
}

// base_w [4096][4096] fp32 -> W' cols 0..4095 fp16
__global__ void conv_w(const float* __restrict__ w, f16* __restrict__ Wp) {
  int rc = blockIdx.x;              // 64 chunks
  int cc = blockIdx.y;              // 4
  int col = cc * 1024 + threadIdx.x * 4;
  long base = (long)rc * 64 * D_DIM + col;
  for (int r = 0; r < 64; ++r) {
    float4 v = *(const float4*)(w + base + (long)r * D_DIM);
    H4 t; t.h[0] = (f16)v.x; t.h[1] = (f16)v.y; t.h[2] = (f16)v.z; t.h[3] = (f16)v.w;
    *(ushort4*)((char*)Wp + ((long)(rc * 64 + r) * KTOT + col) * 2) = t.u;
  }
}

// lora_B [8][4096][16] fp32 -> W' cols 4096..4223 : W'[n][4096+k*16+r] = B[k][n][r]
__global__ void conv_bext(const float* __restrict__ loraB, f16* __restrict__ Wp) {
  int g = blockIdx.x * 256 + threadIdx.x;     // 0..524287
  int n = g >> 7, kr = g & 127;
  int k = kr >> 4, r = kr & 15;
  float v = loraB[((long)k * D_DIM + n) * R_DIM + r];
  Wp[(long)n * KTOT + D_DIM + kr] = (f16)v;
}

// lora_A [8][16][4096] fp32 -> Ah [128][4096] fp16 (flat copy+convert)
__global__ void conv_aext(const float* __restrict__ loraA, f16* __restrict__ Ah) {
  long g = ((long)blockIdx.x * 256 + threadIdx.x) * 4;   // over 524288 elems
  float4 v = *(const float4*)(loraA + g);
  H4 t; t.h[0] = (f16)v.x; t.h[1] = (f16)v.y; t.h[2] = (f16)v.z; t.h[3] = (f16)v.w;
  *(ushort4*)((char*)Ah + g * 2) = t.u;
}

// logits[b][k] = dot(colsum[b], router_w[k]) / S + router_b[k]
__global__ void router_logits(const float* __restrict__ colsum, const float* __restrict__ rw,
                              const float* __restrict__ rb, float* __restrict__ logits) {
  int b = blockIdx.x >> 3, k = blockIdx.x & 7;
  const float* cs = colsum + b * D_DIM;
  const float* w = rw + k * D_DIM;
  float p = 0.f;
  for (int d = threadIdx.x; d < D_DIM; d += 256) p += cs[d] * w[d];
  __shared__ float red[4];
  for (int off = 32; off; off >>= 1) p += __shfl_down(p, off);
  if ((threadIdx.x & 63) == 0) red[threadIdx.x >> 6] = p;
  __syncthreads();
  if (threadIdx.x == 0)
    logits[b * 8 + k] = (red[0] + red[1] + red[2] + red[3]) / (float)S_DIM + rb[k];
}

// softmax over K=8 per batch, times SCALING
__global__ void router_softmax(const float* __restrict__ logits, float* __restrict__ wsc) {
  int lane = threadIdx.x;
  if (lane < 32) {
    float L = logits[lane];
    float m = L;
    m = fmaxf(m, __shfl_xor(m, 1));
    m = fmaxf(m, __shfl_xor(m, 2));
    m = fmaxf(m, __shfl_xor(m, 4));
    float e = __expf(L - m);
    float s = e;
    s += __shfl_xor(s, 1); s += __shfl_xor(s, 2); s += __shfl_xor(s, 4);
    wsc[lane] = e / s * SCALING;
  }
}

// sum 4 K-split partials, scale by router weight, write A' ext cols as fp16
__global__ void combine_h(const float* __restrict__ hp, const float* __restrict__ wsc,
                          f16* __restrict__ Ap) {
  long g = (long)blockIdx.x * 256 + threadIdx.x;    // 0..1048575
  long row = g >> 7; int kr = (int)(g & 127);
  int b = (int)(row >> 11);
  float s = hp[g] + hp[g + 1048576] + hp[g + 2097152] + hp[g + 3145728];
  Ap[row * KTOT + D_DIM + kr] = (f16)(s * wsc[b * 8 + (kr >> 4)]);
}

// MODE 0: C(fp32[M][ldc]) = A@Bt^T + bias   (main fused GEMM)
// MODE 2: h-partial: hp[z][M][128] = A[:, z*1024:(z+1)*1024] @ Bt^T  (K-split)
template <int MODE>
__global__ __launch_bounds__(256, 2) void gemm_bt(
    const f16* __restrict__ A, int lda, const f16* __restrict__ Bt, int ldb,
    int kIters, const float* __restrict__ bias, float* __restrict__ C, int ldc) {
  __shared__ __align__(16) f16 As[128 * 64];
  __shared__ __align__(16) f16 Bs[128 * 64];
  int tid = threadIdx.x;
  int wave = tid >> 6, lane = tid & 63;
  long row0 = (long)blockIdx.x * 128;
  long col0 = (long)blockIdx.y * 128;
  int wr = wave >> 1, wc = wave & 1;
  int fr = lane & 15, fq = lane >> 4;
  int srow = lane >> 3;             // row within an 8-row segment
  int scol = (lane & 7) * 8;        // halfs within the 64-col tile
  long koff = (MODE == 2) ? (long)blockIdx.z * 1024 : 0;

  f32x4 acc[4][4] = {};

  for (int kb = 0; kb < kIters; ++kb) {
    long kbase = (long)kb * 64 + koff;
    for (int i = 0; i < 4; ++i) {
      int seg = i * 4 + wave;
      const f16* ga = A + (row0 + seg * 8 + srow) * lda + kbase + scol;
      load_lds16(ga, (char*)As + seg * 1024);
      const f16* gb = Bt + (col0 + seg * 8 + srow) * ldb + kbase + scol;
      load_lds16(gb, (char*)Bs + seg * 1024);
    }
    __syncthreads();
    for (int ks = 0; ks < 2; ++ks) {
      int kbyte = ks * 64 + fq * 16;
      f16x8 af[4], bf[4];
      for (int mi = 0; mi < 4; ++mi)
        af[mi] = *(const f16x8*)((const char*)As + (wr * 64 + mi * 16 + fr) * 128 + kbyte);
      for (int ni = 0; ni < 4; ++ni)
        bf[ni] = *(const f16x8*)((const char*)Bs + (wc * 64 + ni * 16 + fr) * 128 + kbyte);
      for (int mi = 0; mi < 4; ++mi)
        for (int ni = 0; ni < 4; ++ni)
          acc[mi][ni] = __builtin_amdgcn_mfma_f32_16x16x32_f16(af[mi], bf[ni], acc[mi][ni], 0, 0, 0);
    }
    __syncthreads();
  }

  if (MODE == 0) {
    for (int ni = 0; ni < 4; ++ni) {
      long col = col0 + wc * 64 + ni * 16 + fr;
      float bv = bias[col];
      for (int mi = 0; mi < 4; ++mi) {
        long row = row0 + wr * 64 + mi * 16 + fq * 4;
        float* cp = C + row * ldc + col;
        #pragma unroll
        for (int j = 0; j < 4; ++j) cp[(long)j * ldc] = acc[mi][ni][j] + bv;
      }
    }
  } else {
    long zb = (long)blockIdx.z * (long)M_DIM * 128;
    for (int ni = 0; ni < 4; ++ni) {
      int col = wc * 64 + ni * 16 + fr;
      for (int mi = 0; mi < 4; ++mi) {
        long row = row0 + wr * 64 + mi * 16 + fq * 4;
        float* cp = C + zb + row * 128 + col;
        #pragma unroll
        for (int j = 0; j < 4; ++j) cp[(long)j * 128] = acc[mi][ni][j];
      }
    }
  }
}

extern "C" void kernel_launch(void* const* d_in, const int* in_sizes, int n_in,
                              void* d_out, int out_size, void* d_ws, size_t ws_size,
                              hipStream_t stream) {
  (void)in_sizes; (void)n_in; (void)out_size; (void)ws_size;
  const float* x        = (const float*)d_in[0];
  const float* base_w   = (const float*)d_in[1];
  const float* base_b   = (const float*)d_in[2];
  const float* lora_A   = (const float*)d_in[3];
  const float* lora_B   = (const float*)d_in[4];
  const float* router_w = (const float*)d_in[5];
  const float* router_b = (const float*)d_in[6];
  float* out = (float*)d_out;

  char* ws = (char*)d_ws;
  f16* Ap       = (f16*)(ws + WS_AP);
  f16* Wp       = (f16*)(ws + WS_WP);
  f16* Ah       = (f16*)(ws + WS_AH);
  float* hp     = (float*)(ws + WS_HP);
  float* colsum = (float*)(ws + WS_CS);
  float* logits = (float*)(ws + WS_LG);
  float* wsc    = (float*)(ws + WS_WS);

  hipMemsetAsync(colsum, 0, 65536, stream);
  conv_x<<<dim3(128, 4), 256, 0, stream>>>(x, Ap, colsum);
  conv_w<<<dim3(64, 4), 256, 0, stream>>>(base_w, Wp);
  conv_bext<<<2048, 256, 0, stream>>>(lora_B, Wp);
  conv_aext<<<512, 256, 0, stream>>>(lora_A, Ah);
  router_logits<<<32, 256, 0, stream>>>(colsum, router_w, router_b, logits);
  router_softmax<<<1, 64, 0, stream>>>(logits, wsc);
  // h partials: M=8192, N=128, K split 4x1024
  gemm_bt<2><<<dim3(64, 1, 4), 256, 0, stream>>>(Ap, KTOT, Ah, D_DIM, 16, nullptr, hp, 128);
  combine_h<<<4096, 256, 0, stream>>>(hp, wsc, Ap);
  // main fused GEMM: out = [x|h'] @ [W|Bcat]^T + bias
  gemm_bt<0><<<dim3(64, 32), 256, 0, stream>>>(Ap, KTOT, Wp, KTOT, 66, base_b, out, D_DIM);
}

// Round 2
// 589.009 us; speedup vs baseline: 1.1094x; 1.1094x over previous
//
#include <hip/hip_runtime.h>
#include <hip/hip_fp16.h>
#include <stdint.h>

typedef _Float16 f16;
typedef __attribute__((ext_vector_type(8))) _Float16 f16x8;
typedef __attribute__((ext_vector_type(4))) float f32x4;

#define D_DIM 4096
#define S_DIM 2048
#define M_DIM 8192   // B*S
#define R_DIM 16
#define KR 128       // K_experts * R
#define KTOT 4224    // D + KR
#define NKT 66       // KTOT / 64
#define SCALING 2.0f

// ---- ws layout (bytes) ----
#define WS_AP    0                  // A' fp16 [8192][4224]  = 69,206,016
#define WS_WP    69206016           // W' fp16 [4096][4224]  = 34,603,008
#define WS_AH    103809024          // Ah fp16 [128][4096]   =  1,048,576
#define WS_HP    104857600          // h partials fp32 [4][8192][128] = 16,777,216
#define WS_PART  121634816          // colsum partials fp32 [128][4096] = 2,097,152
#define WS_LG    123731968          // logits fp32 [32]
#define WS_WS    123732096          // weights*2.0 fp32 [32]

__device__ __forceinline__ void load_lds16(const void* g, void* l) {
  __builtin_amdgcn_global_load_lds(
      (const __attribute__((address_space(1))) void*)g,
      (__attribute__((address_space(3))) void*)l, 16, 0, 0);
}

union H4 { f16 h[4]; ushort4 u; };

// x [8192][4096] fp32 -> A' cols 0..4095 fp16 ; per-64-row-chunk column sums (no atomics)
__global__ void conv_x(const float* __restrict__ x, f16* __restrict__ Ap,
                       float* __restrict__ part) {
  int rc = blockIdx.x;              // 64-row chunk (128 chunks)
  int cc = blockIdx.y;              // 1024-col chunk (4)
  int col = cc * 1024 + threadIdx.x * 4;
  long base = (long)rc * 64 * D_DIM + col;
  float s0 = 0, s1 = 0, s2 = 0, s3 = 0;
  for (int r = 0; r < 64; ++r) {
    float4 v = *(const float4*)(x + base + (long)r * D_DIM);
    H4 t; t.h[0] = (f16)v.x; t.h[1] = (f16)v.y; t.h[2] = (f16)v.z; t.h[3] = (f16)v.w;
    *(ushort4*)((char*)Ap + ((long)(rc * 64 + r) * KTOT + col) * 2) = t.u;
    s0 += v.x; s1 += v.y; s2 += v.z; s3 += v.w;
  }
  float4 sv; sv.x = s0; sv.y = s1; sv.z = s2; sv.w = s3;
  *(float4*)(part + (long)rc * D_DIM + col) = sv;
}

// base_w [4096][4096] fp32 -> W' cols 0..4095 fp16
__global__ void conv_w(const float* __restrict__ w, f16* __restrict__ Wp) {
  int rc = blockIdx.x;              // 64 chunks
  int cc = blockIdx.y;              // 4
  int col = cc * 1024 + threadIdx.x * 4;
  long base = (long)rc * 64 * D_DIM + col;
  for (int r = 0; r < 64; ++r) {
    float4 v = *(const float4*)(w + base + (long)r * D_DIM);
    H4 t; t.h[0] = (f16)v.x; t.h[1] = (f16)v.y; t.h[2] = (f16)v.z; t.h[3] = (f16)v.w;
    *(ushort4*)((char*)Wp + ((long)(rc * 64 + r) * KTOT + col) * 2) = t.u;
  }
}

// lora_B [8][4096][16] fp32 -> W' cols 4096..4223 : W'[n][4096+k*16+r] = B[k][n][r]
__global__ void conv_bext(const float* __restrict__ loraB, f16* __restrict__ Wp) {
  int g = blockIdx.x * 256 + threadIdx.x;     // 0..524287
  int n = g >> 7, kr = g & 127;
  int k = kr >> 4, r = kr & 15;
  float v = loraB[((long)k * D_DIM + n) * R_DIM + r];
  Wp[(long)n * KTOT + D_DIM + kr] = (f16)v;
}

// lora_A [8][16][4096] fp32 -> Ah [128][4096] fp16 (flat copy+convert)
__global__ void conv_aext(const float* __restrict__ loraA, f16* __restrict__ Ah) {
  long g = ((long)blockIdx.x * 256 + threadIdx.x) * 4;   // over 524288 elems
  float4 v = *(const float4*)(loraA + g);
  H4 t; t.h[0] = (f16)v.x; t.h[1] = (f16)v.y; t.h[2] = (f16)v.z; t.h[3] = (f16)v.w;
  *(ushort4*)((char*)Ah + g * 2) = t.u;
}

// logits[b][k] = dot(colmean[b], router_w[k]) + router_b[k]; colsum from 32 chunk-partials
__global__ void router_logits(const float* __restrict__ part, const float* __restrict__ rw,
                              const float* __restrict__ rb, float* __restrict__ logits) {
  int b = blockIdx.x >> 3, k = blockIdx.x & 7;
  const float* w = rw + k * D_DIM;
  float p = 0.f;
  for (int d = threadIdx.x; d < D_DIM; d += 256) {
    float s = 0.f;
    #pragma unroll 8
    for (int i = 0; i < 32; ++i) s += part[(long)(b * 32 + i) * D_DIM + d];
    p += s * w[d];
  }
  __shared__ float red[4];
  for (int off = 32; off; off >>= 1) p += __shfl_down(p, off);
  if ((threadIdx.x & 63) == 0) red[threadIdx.x >> 6] = p;
  __syncthreads();
  if (threadIdx.x == 0)
    logits[b * 8 + k] = (red[0] + red[1] + red[2] + red[3]) / (float)S_DIM + rb[k];
}

// softmax over K=8 per batch, times SCALING
__global__ void router_softmax(const float* __restrict__ logits, float* __restrict__ wsc) {
  int lane = threadIdx.x;
  if (lane < 32) {
    float L = logits[lane];
    float m = L;
    m = fmaxf(m, __shfl_xor(m, 1));
    m = fmaxf(m, __shfl_xor(m, 2));
    m = fmaxf(m, __shfl_xor(m, 4));
    float e = __expf(L - m);
    float s = e;
    s += __shfl_xor(s, 1); s += __shfl_xor(s, 2); s += __shfl_xor(s, 4);
    wsc[lane] = e / s * SCALING;
  }
}

// sum 4 K-split partials, scale by router weight, write A' ext cols as fp16
__global__ void combine_h(const float* __restrict__ hp, const float* __restrict__ wsc,
                          f16* __restrict__ Ap) {
  long g = (long)blockIdx.x * 256 + threadIdx.x;    // 0..1048575
  long row = g >> 7; int kr = (int)(g & 127);
  int b = (int)(row >> 11);
  float s = hp[g] + hp[g + 1048576] + hp[g + 2097152] + hp[g + 3145728];
  Ap[row * KTOT + D_DIM + kr] = (f16)(s * wsc[b * 8 + (kr >> 4)]);
}

// ---------------- small 128^2 GEMM (h-partial path only) ----------------
// hp[z][M][128] = A[:, z*1024:(z+1)*1024] @ Bt^T  (K-split over blockIdx.z)
__global__ __launch_bounds__(256, 2) void gemm_h(
    const f16* __restrict__ A, int lda, const f16* __restrict__ Bt, int ldb,
    int kIters, float* __restrict__ C) {
  __shared__ __align__(16) f16 As[128 * 64];
  __shared__ __align__(16) f16 Bs[128 * 64];
  int tid = threadIdx.x;
  int wave = tid >> 6, lane = tid & 63;
  long row0 = (long)blockIdx.x * 128;
  long col0 = 0;
  int wr = wave >> 1, wc = wave & 1;
  int fr = lane & 15, fq = lane >> 4;
  int srow = lane >> 3;
  int scol = (lane & 7) * 8;
  long koff = (long)blockIdx.z * 1024;

  f32x4 acc[4][4] = {};

  for (int kb = 0; kb < kIters; ++kb) {
    long kbase = (long)kb * 64 + koff;
    for (int i = 0; i < 4; ++i) {
      int seg = i * 4 + wave;
      const f16* ga = A + (row0 + seg * 8 + srow) * lda + kbase + scol;
      load_lds16(ga, (char*)As + seg * 1024);
      const f16* gb = Bt + (col0 + seg * 8 + srow) * ldb + kbase + scol;
      load_lds16(gb, (char*)Bs + seg * 1024);
    }
    __syncthreads();
    for (int ks = 0; ks < 2; ++ks) {
      int kbyte = ks * 64 + fq * 16;
      f16x8 af[4], bf[4];
      for (int mi = 0; mi < 4; ++mi)
        af[mi] = *(const f16x8*)((const char*)As + (wr * 64 + mi * 16 + fr) * 128 + kbyte);
      for (int ni = 0; ni < 4; ++ni)
        bf[ni] = *(const f16x8*)((const char*)Bs + (wc * 64 + ni * 16 + fr) * 128 + kbyte);
      for (int mi = 0; mi < 4; ++mi)
        for (int ni = 0; ni < 4; ++ni)
          acc[mi][ni] = __builtin_amdgcn_mfma_f32_16x16x32_f16(af[mi], bf[ni], acc[mi][ni], 0, 0, 0);
    }
    __syncthreads();
  }

  long zb = (long)blockIdx.z * (long)M_DIM * 128;
  for (int ni = 0; ni < 4; ++ni) {
    int col = wc * 64 + ni * 16 + fr;
    for (int mi = 0; mi < 4; ++mi) {
      long row = row0 + wr * 64 + mi * 16 + fq * 4;
      float* cp = C + zb + row * 128 + col;
      #pragma unroll
      for (int j = 0; j < 4; ++j) cp[(long)j * 128] = acc[mi][ni][j];
    }
  }
}

// ---------------- main 256^2 GEMM: counted-vmcnt pipeline + T2 swizzle + T1 ----------------
// out[M][ldc] = A[M][lda] @ Bt[N][ldb]^T + bias, K = nkt*64
//
// LDS: 2 dbuf x (A 256x64 f16 = 32KB + B 32KB) = 128 KB. 1 block/CU, 8 waves.
// Swizzle: LDS byte offset within a 128B row: off ^= (row&7)<<4 (both-sides: inverse
// applied to the per-lane GLOBAL source addr feeding linear global_load_lds, same XOR
// on ds_read addr). Residual 2-way bank conflict = free.
// Pipeline: stage tile t+2 after the "reads of buf done" barrier; s_waitcnt vmcnt(8)
// keeps exactly one K-tile (8 loads/thread) in flight across each compute phase.
__device__ __forceinline__ void stage256(const f16* __restrict__ G, long row0, int ld,
                                         long kbase, char* ldsT, int tid) {
  int lr = tid >> 3;                                        // row within 64-row round
  int sw = (((tid & 7) * 16) ^ ((lr & 7) << 4)) >> 1;       // pre-swizzled col (f16 units)
  char* wbase = ldsT + ((tid >> 6) << 10);                  // wave-uniform LDS base
  #pragma unroll
  for (int j = 0; j < 4; ++j) {
    const f16* g = G + (row0 + j * 64 + lr) * (long)ld + kbase + sw;
    load_lds16(g, wbase + j * 8192);
  }
}

__global__ __launch_bounds__(512, 2) void gemm256(
    const f16* __restrict__ A, int lda, const f16* __restrict__ Bt, int ldb,
    int nkt, const float* __restrict__ bias, float* __restrict__ C, int ldc) {
  __shared__ __align__(16) char smem[131072];
  int tid = threadIdx.x;
  int wave = tid >> 6, lane = tid & 63;
  int wr = wave >> 2, wc = wave & 3;        // 2 x 4 wave grid; wave tile 128 x 64
  int fr = lane & 15, fq = lane >> 4;

  // bijective XCD swizzle: 512 wgs = 64 per XCD; n-tile fastest within an XCD so the
  // 2.1MB A-panel stays L2-resident across 16 consecutive blocks.
  int flat = blockIdx.x;
  int wg = (flat & 7) * 64 + (flat >> 3);
  long row0 = (long)(wg >> 4) * 256;
  long col0 = (long)(wg & 15) * 256;

  f32x4 acc[8][4] = {};

  // prologue: stage tiles 0 and 1
  stage256(A,  row0, lda, 0,  smem,          tid);
  stage256(Bt, col0, ldb, 0,  smem + 32768,  tid);
  stage256(A,  row0, lda, 64, smem + 65536,  tid);
  stage256(Bt, col0, ldb, 64, smem + 98304,  tid);
  asm volatile("s_waitcnt vmcnt(8)" ::: "memory");   // tile 0 landed
  asm volatile("s_barrier" ::: "memory");

  int cur = 0;
  int sw = (fr & 7) << 4;
  for (int t = 0; t < nkt; ++t) {
    const char* Ab = smem + cur * 65536;
    const char* Bb = Ab + 32768;
    #pragma unroll
    for (int qm = 0; qm < 2; ++qm) {
      f16x8 af[4][2];
      #pragma unroll
      for (int m2 = 0; m2 < 4; ++m2) {
        int row = wr * 128 + (qm * 4 + m2) * 16 + fr;
        af[m2][0] = *(const f16x8*)(Ab + row * 128 + ((fq * 16) ^ sw));
        af[m2][1] = *(const f16x8*)(Ab + row * 128 + ((64 + fq * 16) ^ sw));
      }
      #pragma unroll
      for (int qn = 0; qn < 2; ++qn) {
        f16x8 bf[2][2];
        #pragma unroll
        for (int n2 = 0; n2 < 2; ++n2) {
          int rowb = wc * 64 + (qn * 2 + n2) * 16 + fr;
          bf[n2][0] = *(const f16x8*)(Bb + rowb * 128 + ((fq * 16) ^ sw));
          bf[n2][1] = *(const f16x8*)(Bb + rowb * 128 + ((64 + fq * 16) ^ sw));
        }
        #pragma unroll
        for (int m2 = 0; m2 < 4; ++m2)
          #pragma unroll
          for (int n2 = 0; n2 < 2; ++n2) {
            f32x4* a = &acc[qm * 4 + m2][qn * 2 + n2];
            *a = __builtin_amdgcn_mfma_f32_16x16x32_f16(af[m2][0], bf[n2][0], *a, 0, 0, 0);
            *a = __builtin_amdgcn_mfma_f32_16x16x32_f16(af[m2][1], bf[n2][1], *a, 0, 0, 0);
          }
      }
    }
    asm volatile("s_barrier" ::: "memory");           // all waves done reading buf[cur]
    if (t + 2 < nkt) {
      stage256(A,  row0, lda, (long)(t + 2) * 64, smem + cur * 65536,         tid);
      stage256(Bt, col0, ldb, (long)(t + 2) * 64, smem + cur * 65536 + 32768, tid);
      asm volatile("s_waitcnt vmcnt(8)" ::: "memory"); // tile t+1 fully landed
    } else {
      asm volatile("s_waitcnt vmcnt(0)" ::: "memory"); // drain tail
    }
    asm volatile("s_barrier" ::: "memory");
    cur ^= 1;
  }

  #pragma unroll
  for (int ni = 0; ni < 4; ++ni) {
    long col = col0 + wc * 64 + ni * 16 + fr;
    float bv = bias[col];
    #pragma unroll
    for (int mi = 0; mi < 8; ++mi) {
      long row = row0 + wr * 128 + mi * 16 + fq * 4;
      float* cp = C + row * ldc + col;
      #pragma unroll
      for (int j = 0; j < 4; ++j) cp[(long)j * ldc] = acc[mi][ni][j] + bv;
    }
  }
}

extern "C" void kernel_launch(void* const* d_in, const int* in_sizes, int n_in,
                              void* d_out, int out_size, void* d_ws, size_t ws_size,
                              hipStream_t stream) {
  (void)in_sizes; (void)n_in; (void)out_size; (void)ws_size;
  const float* x        = (const float*)d_in[0];
  const float* base_w   = (const float*)d_in[1];
  const float* base_b   = (const float*)d_in[2];
  const float* lora_A   = (const float*)d_in[3];
  const float* lora_B   = (const float*)d_in[4];
  const float* router_w = (const float*)d_in[5];
  const float* router_b = (const float*)d_in[6];
  float* out = (float*)d_out;

  char* ws = (char*)d_ws;
  f16* Ap       = (f16*)(ws + WS_AP);
  f16* Wp       = (f16*)(ws + WS_WP);
  f16* Ah       = (f16*)(ws + WS_AH);
  float* hp     = (float*)(ws + WS_HP);
  float* part   = (float*)(ws + WS_PART);
  float* logits = (float*)(ws + WS_LG);
  float* wsc    = (float*)(ws + WS_WS);

  conv_x<<<dim3(128, 4), 256, 0, stream>>>(x, Ap, part);
  conv_w<<<dim3(64, 4), 256, 0, stream>>>(base_w, Wp);
  conv_bext<<<2048, 256, 0, stream>>>(lora_B, Wp);
  conv_aext<<<512, 256, 0, stream>>>(lora_A, Ah);
  router_logits<<<32, 256, 0, stream>>>(part, router_w, router_b, logits);
  router_softmax<<<1, 64, 0, stream>>>(logits, wsc);
  // h partials: M=8192, N=128, K split 4x1024
  gemm_h<<<dim3(64, 1, 4), 256, 0, stream>>>(Ap, KTOT, Ah, D_DIM, 16, hp);
  combine_h<<<4096, 256, 0, stream>>>(hp, wsc, Ap);
  // main fused GEMM: out = [x|h'] @ [W|Bcat]^T + bias  (K = 4224 = 66*64)
  gemm256<<<512, 512, 0, stream>>>(Ap, KTOT, Wp, KTOT, NKT, base_b, out, D_DIM);
}

// Round 3
// 588.704 us; speedup vs baseline: 1.1100x; 1.0005x over previous
//
#include <hip/hip_runtime.h>
#include <hip/hip_fp16.h>
#include <stdint.h>

typedef _Float16 f16;
typedef __attribute__((ext_vector_type(8))) _Float16 f16x8;
typedef __attribute__((ext_vector_type(4))) float f32x4;

#define D_DIM 4096
#define S_DIM 2048
#define M_DIM 8192   // B*S
#define R_DIM 16
#define KR 128       // K_experts * R
#define KTOT 4224    // D + KR
#define NKT 66       // KTOT / 64
#define SCALING 2.0f

// ---- ws layout (bytes) ----
#define WS_AP    0                  // A' fp16 [8192][4224]  = 69,206,016
#define WS_WP    69206016           // W' fp16 [4096][4224]  = 34,603,008
#define WS_AH    103809024          // Ah fp16 [128][4096]   =  1,048,576
#define WS_HP    104857600          // h partials fp32 [4][8192][128] = 16,777,216
#define WS_PART  121634816          // colsum partials fp32 [128][4096] = 2,097,152
#define WS_LG    123731968          // logits fp32 [32]
#define WS_WS    123732096          // weights*2.0 fp32 [32]

__device__ __forceinline__ void load_lds16(const void* g, void* l) {
  __builtin_amdgcn_global_load_lds(
      (const __attribute__((address_space(1))) void*)g,
      (__attribute__((address_space(3))) void*)l, 16, 0, 0);
}

union H4 { f16 h[4]; ushort4 u; };

// x [8192][4096] fp32 -> A' cols 0..4095 fp16 ; per-64-row-chunk column sums (no atomics)
__global__ void conv_x(const float* __restrict__ x, f16* __restrict__ Ap,
                       float* __restrict__ part) {
  int rc = blockIdx.x;              // 64-row chunk (128 chunks)
  int cc = blockIdx.y;              // 1024-col chunk (4)
  int col = cc * 1024 + threadIdx.x * 4;
  long base = (long)rc * 64 * D_DIM + col;
  float s0 = 0, s1 = 0, s2 = 0, s3 = 0;
  for (int r = 0; r < 64; ++r) {
    float4 v = *(const float4*)(x + base + (long)r * D_DIM);
    H4 t; t.h[0] = (f16)v.x; t.h[1] = (f16)v.y; t.h[2] = (f16)v.z; t.h[3] = (f16)v.w;
    *(ushort4*)((char*)Ap + ((long)(rc * 64 + r) * KTOT + col) * 2) = t.u;
    s0 += v.x; s1 += v.y; s2 += v.z; s3 += v.w;
  }
  float4 sv; sv.x = s0; sv.y = s1; sv.z = s2; sv.w = s3;
  *(float4*)(part + (long)rc * D_DIM + col) = sv;
}

// base_w [4096][4096] fp32 -> W' cols 0..4095 fp16
__global__ void conv_w(const float* __restrict__ w, f16* __restrict__ Wp) {
  int rc = blockIdx.x;              // 64 chunks
  int cc = blockIdx.y;              // 4
  int col = cc * 1024 + threadIdx.x * 4;
  long base = (long)rc * 64 * D_DIM + col;
  for (int r = 0; r < 64; ++r) {
    float4 v = *(const float4*)(w + base + (long)r * D_DIM);
    H4 t; t.h[0] = (f16)v.x; t.h[1] = (f16)v.y; t.h[2] = (f16)v.z; t.h[3] = (f16)v.w;
    *(ushort4*)((char*)Wp + ((long)(rc * 64 + r) * KTOT + col) * 2) = t.u;
  }
}

// lora_B [8][4096][16] fp32 -> W' cols 4096..4223 : W'[n][4096+k*16+r] = B[k][n][r]
__global__ void conv_bext(const float* __restrict__ loraB, f16* __restrict__ Wp) {
  int g = blockIdx.x * 256 + threadIdx.x;     // 0..524287
  int n = g >> 7, kr = g & 127;
  int k = kr >> 4, r = kr & 15;
  float v = loraB[((long)k * D_DIM + n) * R_DIM + r];
  Wp[(long)n * KTOT + D_DIM + kr] = (f16)v;
}

// lora_A [8][16][4096] fp32 -> Ah [128][4096] fp16 (flat copy+convert)
__global__ void conv_aext(const float* __restrict__ loraA, f16* __restrict__ Ah) {
  long g = ((long)blockIdx.x * 256 + threadIdx.x) * 4;   // over 524288 elems
  float4 v = *(const float4*)(loraA + g);
  H4 t; t.h[0] = (f16)v.x; t.h[1] = (f16)v.y; t.h[2] = (f16)v.z; t.h[3] = (f16)v.w;
  *(ushort4*)((char*)Ah + g * 2) = t.u;
}

// logits[b][k] = dot(colmean[b], router_w[k]) + router_b[k]; colsum from 32 chunk-partials
__global__ void router_logits(const float* __restrict__ part, const float* __restrict__ rw,
                              const float* __restrict__ rb, float* __restrict__ logits) {
  int b = blockIdx.x >> 3, k = blockIdx.x & 7;
  const float* w = rw + k * D_DIM;
  float p = 0.f;
  for (int d = threadIdx.x; d < D_DIM; d += 256) {
    float s = 0.f;
    #pragma unroll 8
    for (int i = 0; i < 32; ++i) s += part[(long)(b * 32 + i) * D_DIM + d];
    p += s * w[d];
  }
  __shared__ float red[4];
  for (int off = 32; off; off >>= 1) p += __shfl_down(p, off);
  if ((threadIdx.x & 63) == 0) red[threadIdx.x >> 6] = p;
  __syncthreads();
  if (threadIdx.x == 0)
    logits[b * 8 + k] = (red[0] + red[1] + red[2] + red[3]) / (float)S_DIM + rb[k];
}

// softmax over K=8 per batch, times SCALING
__global__ void router_softmax(const float* __restrict__ logits, float* __restrict__ wsc) {
  int lane = threadIdx.x;
  if (lane < 32) {
    float L = logits[lane];
    float m = L;
    m = fmaxf(m, __shfl_xor(m, 1));
    m = fmaxf(m, __shfl_xor(m, 2));
    m = fmaxf(m, __shfl_xor(m, 4));
    float e = __expf(L - m);
    float s = e;
    s += __shfl_xor(s, 1); s += __shfl_xor(s, 2); s += __shfl_xor(s, 4);
    wsc[lane] = e / s * SCALING;
  }
}

// sum 4 K-split partials, scale by router weight, write A' ext cols as fp16
__global__ void combine_h(const float* __restrict__ hp, const float* __restrict__ wsc,
                          f16* __restrict__ Ap) {
  long g = (long)blockIdx.x * 256 + threadIdx.x;    // 0..1048575
  long row = g >> 7; int kr = (int)(g & 127);
  int b = (int)(row >> 11);
  float s = hp[g] + hp[g + 1048576] + hp[g + 2097152] + hp[g + 3145728];
  Ap[row * KTOT + D_DIM + kr] = (f16)(s * wsc[b * 8 + (kr >> 4)]);
}

// ---- staging helpers: linear LDS dest + pre-swizzled global source (T2, rule #21) ----
// 512-thread version: 64 rows/round, 4 rounds (256-row tile)
__device__ __forceinline__ void stage256(const f16* __restrict__ G, long row0, int ld,
                                         long kbase, char* ldsT, int tid) {
  int lr = tid >> 3;                                        // 0..63
  int sw = (((tid & 7) * 16) ^ ((lr & 7) << 4)) >> 1;       // pre-swizzled col (f16 units)
  char* wbase = ldsT + ((tid >> 6) << 10);                  // wave-uniform LDS base
  #pragma unroll
  for (int j = 0; j < 4; ++j) {
    const f16* g = G + (row0 + j * 64 + lr) * (long)ld + kbase + sw;
    load_lds16(g, wbase + j * 8192);
  }
}
// 256-thread version: 32 rows/round, 4 rounds (128-row tile)
__device__ __forceinline__ void stage128(const f16* __restrict__ G, long row0, int ld,
                                         long kbase, char* ldsT, int tid) {
  int lr = tid >> 3;                                        // 0..31
  int sw = (((tid & 7) * 16) ^ ((lr & 7) << 4)) >> 1;
  char* wbase = ldsT + ((tid >> 6) << 10);
  #pragma unroll
  for (int j = 0; j < 4; ++j) {
    const f16* g = G + (row0 + j * 32 + lr) * (long)ld + kbase + sw;
    load_lds16(g, wbase + j * 4096);
  }
}

// ---------------- h-path GEMM: 128x128 tile, counted-vmcnt pipeline, 2 blocks/CU -------
// hp[z][M][128] = A[:, z*1024:(z+1)*1024] @ Bt[0:128,:]^T   (z = blockIdx.y)
__global__ __launch_bounds__(256, 2) void gemm_h2(
    const f16* __restrict__ A, int lda, const f16* __restrict__ Bt, int ldb,
    float* __restrict__ hp) {
  __shared__ __align__(16) char smem[65536];   // dbuf x (A 16K + B 16K)
  int tid = threadIdx.x;
  int wave = tid >> 6, lane = tid & 63;
  int wr = wave >> 1, wc = wave & 1;           // 2x2 waves; wave tile 64x64
  int fr = lane & 15, fq = lane >> 4;
  long row0 = (long)blockIdx.x * 128;
  long koff = (long)blockIdx.y * 1024;

  f32x4 acc[4][4] = {};

  stage128(A,  row0, lda, koff,      smem,         tid);
  stage128(Bt, 0,    ldb, koff,      smem + 16384, tid);
  stage128(A,  row0, lda, koff + 64, smem + 32768, tid);
  stage128(Bt, 0,    ldb, koff + 64, smem + 49152, tid);
  asm volatile("s_waitcnt vmcnt(8)" ::: "memory");
  asm volatile("s_barrier" ::: "memory");

  int cur = 0;
  int sw = (fr & 7) << 4;
  for (int t = 0; t < 16; ++t) {
    const char* Ab = smem + cur * 32768;
    const char* Bb = Ab + 16384;
    __builtin_amdgcn_s_setprio(1);
    #pragma unroll
    for (int ks = 0; ks < 2; ++ks) {
      int kb = ks * 64 + fq * 16;
      f16x8 af[4], bf[4];
      #pragma unroll
      for (int mi = 0; mi < 4; ++mi)
        af[mi] = *(const f16x8*)(Ab + (wr * 64 + mi * 16 + fr) * 128 + (kb ^ sw));
      #pragma unroll
      for (int ni = 0; ni < 4; ++ni)
        bf[ni] = *(const f16x8*)(Bb + (wc * 64 + ni * 16 + fr) * 128 + (kb ^ sw));
      #pragma unroll
      for (int mi = 0; mi < 4; ++mi)
        #pragma unroll
        for (int ni = 0; ni < 4; ++ni)
          acc[mi][ni] = __builtin_amdgcn_mfma_f32_16x16x32_f16(af[mi], bf[ni], acc[mi][ni], 0, 0, 0);
    }
    __builtin_amdgcn_s_setprio(0);
    asm volatile("s_barrier" ::: "memory");     // all waves done reading buf[cur]
    if (t + 2 < 16) {
      stage128(A,  row0, lda, koff + (t + 2) * 64, smem + cur * 32768,         tid);
      stage128(Bt, 0,    ldb, koff + (t + 2) * 64, smem + cur * 32768 + 16384, tid);
      asm volatile("s_waitcnt vmcnt(8)" ::: "memory");  // tile t+1 landed
    } else {
      asm volatile("s_waitcnt vmcnt(0)" ::: "memory");
    }
    asm volatile("s_barrier" ::: "memory");
    cur ^= 1;
  }

  long zb = (long)blockIdx.y * (long)M_DIM * 128;
  #pragma unroll
  for (int ni = 0; ni < 4; ++ni) {
    int col = wc * 64 + ni * 16 + fr;
    #pragma unroll
    for (int mi = 0; mi < 4; ++mi) {
      long row = row0 + wr * 64 + mi * 16 + fq * 4;
      float* cp = hp + zb + row * 128 + col;
      #pragma unroll
      for (int j = 0; j < 4; ++j) cp[(long)j * 128] = acc[mi][ni][j];
    }
  }
}

// ---------------- main 256^2 GEMM: counted-vmcnt pipeline + T2 swizzle + T1 + T5 -------
__global__ __launch_bounds__(512, 2) void gemm256(
    const f16* __restrict__ A, int lda, const f16* __restrict__ Bt, int ldb,
    int nkt, const float* __restrict__ bias, float* __restrict__ C, int ldc) {
  __shared__ __align__(16) char smem[131072];
  int tid = threadIdx.x;
  int wave = tid >> 6, lane = tid & 63;
  int wr = wave >> 2, wc = wave & 3;        // 2 x 4 wave grid; wave tile 128 x 64
  int fr = lane & 15, fq = lane >> 4;

  // bijective XCD swizzle: 512 wgs = 64 per XCD; n-tile fastest within an XCD
  int flat = blockIdx.x;
  int wg = (flat & 7) * 64 + (flat >> 3);
  long row0 = (long)(wg >> 4) * 256;
  long col0 = (long)(wg & 15) * 256;

  f32x4 acc[8][4] = {};

  stage256(A,  row0, lda, 0,  smem,          tid);
  stage256(Bt, col0, ldb, 0,  smem + 32768,  tid);
  stage256(A,  row0, lda, 64, smem + 65536,  tid);
  stage256(Bt, col0, ldb, 64, smem + 98304,  tid);
  asm volatile("s_waitcnt vmcnt(8)" ::: "memory");   // tile 0 landed
  asm volatile("s_barrier" ::: "memory");

  int cur = 0;
  int sw = (fr & 7) << 4;
  for (int t = 0; t < nkt; ++t) {
    const char* Ab = smem + cur * 65536;
    const char* Bb = Ab + 32768;
    __builtin_amdgcn_s_setprio(1);
    #pragma unroll
    for (int qm = 0; qm < 2; ++qm) {
      f16x8 af[4][2];
      #pragma unroll
      for (int m2 = 0; m2 < 4; ++m2) {
        int row = wr * 128 + (qm * 4 + m2) * 16 + fr;
        af[m2][0] = *(const f16x8*)(Ab + row * 128 + ((fq * 16) ^ sw));
        af[m2][1] = *(const f16x8*)(Ab + row * 128 + ((64 + fq * 16) ^ sw));
      }
      #pragma unroll
      for (int qn = 0; qn < 2; ++qn) {
        f16x8 bf[2][2];
        #pragma unroll
        for (int n2 = 0; n2 < 2; ++n2) {
          int rowb = wc * 64 + (qn * 2 + n2) * 16 + fr;
          bf[n2][0] = *(const f16x8*)(Bb + rowb * 128 + ((fq * 16) ^ sw));
          bf[n2][1] = *(const f16x8*)(Bb + rowb * 128 + ((64 + fq * 16) ^ sw));
        }
        #pragma unroll
        for (int m2 = 0; m2 < 4; ++m2)
          #pragma unroll
          for (int n2 = 0; n2 < 2; ++n2) {
            f32x4* a = &acc[qm * 4 + m2][qn * 2 + n2];
            *a = __builtin_amdgcn_mfma_f32_16x16x32_f16(af[m2][0], bf[n2][0], *a, 0, 0, 0);
            *a = __builtin_amdgcn_mfma_f32_16x16x32_f16(af[m2][1], bf[n2][1], *a, 0, 0, 0);
          }
      }
    }
    __builtin_amdgcn_s_setprio(0);
    asm volatile("s_barrier" ::: "memory");           // all waves done reading buf[cur]
    if (t + 2 < nkt) {
      stage256(A,  row0, lda, (long)(t + 2) * 64, smem + cur * 65536,         tid);
      stage256(Bt, col0, ldb, (long)(t + 2) * 64, smem + cur * 65536 + 32768, tid);
      asm volatile("s_waitcnt vmcnt(8)" ::: "memory"); // tile t+1 fully landed
    } else {
      asm volatile("s_waitcnt vmcnt(0)" ::: "memory"); // drain tail
    }
    asm volatile("s_barrier" ::: "memory");
    cur ^= 1;
  }

  #pragma unroll
  for (int ni = 0; ni < 4; ++ni) {
    long col = col0 + wc * 64 + ni * 16 + fr;
    float bv = bias[col];
    #pragma unroll
    for (int mi = 0; mi < 8; ++mi) {
      long row = row0 + wr * 128 + mi * 16 + fq * 4;
      float* cp = C + row * ldc + col;
      #pragma unroll
      for (int j = 0; j < 4; ++j) cp[(long)j * ldc] = acc[mi][ni][j] + bv;
    }
  }
}

extern "C" void kernel_launch(void* const* d_in, const int* in_sizes, int n_in,
                              void* d_out, int out_size, void* d_ws, size_t ws_size,
                              hipStream_t stream) {
  (void)in_sizes; (void)n_in; (void)out_size; (void)ws_size;
  const float* x        = (const float*)d_in[0];
  const float* base_w   = (const float*)d_in[1];
  const float* base_b   = (const float*)d_in[2];
  const float* lora_A   = (const float*)d_in[3];
  const float* lora_B   = (const float*)d_in[4];
  const float* router_w = (const float*)d_in[5];
  const float* router_b = (const float*)d_in[6];
  float* out = (float*)d_out;

  char* ws = (char*)d_ws;
  f16* Ap       = (f16*)(ws + WS_AP);
  f16* Wp       = (f16*)(ws + WS_WP);
  f16* Ah       = (f16*)(ws + WS_AH);
  float* hp     = (float*)(ws + WS_HP);
  float* part   = (float*)(ws + WS_PART);
  float* logits = (float*)(ws + WS_LG);
  float* wsc    = (float*)(ws + WS_WS);

  conv_x<<<dim3(128, 4), 256, 0, stream>>>(x, Ap, part);
  conv_w<<<dim3(64, 4), 256, 0, stream>>>(base_w, Wp);
  conv_bext<<<2048, 256, 0, stream>>>(lora_B, Wp);
  conv_aext<<<512, 256, 0, stream>>>(lora_A, Ah);
  router_logits<<<32, 256, 0, stream>>>(part, router_w, router_b, logits);
  router_softmax<<<1, 64, 0, stream>>>(logits, wsc);
  // h partials: M=8192, N=128, K split 4x1024 — pipelined 128^2 tiles
  gemm_h2<<<dim3(64, 4), 256, 0, stream>>>(Ap, KTOT, Ah, D_DIM, hp);
  combine_h<<<4096, 256, 0, stream>>>(hp, wsc, Ap);
  // main fused GEMM: out = [x|h'] @ [W|Bcat]^T + bias  (K = 4224 = 66*64)
  gemm256<<<512, 512, 0, stream>>>(Ap, KTOT, Wp, KTOT, NKT, base_b, out, D_DIM);
}